// Round 1
// baseline (176.742 us; speedup 1.0000x reference)
//
#include <hip/hip_runtime.h>
#include <hip/hip_bf16.h>
#include <cstdint>

typedef float f32x4 __attribute__((ext_vector_type(4)));
typedef short bf16x8 __attribute__((ext_vector_type(8)));

#define P_TOT 8192      // B*L
#define KH 768          // K*H
#define EPS_ 1e-5f

__device__ __forceinline__ unsigned short f2bf(float f) {
    unsigned int x = __float_as_uint(f);
    unsigned int r = (x + 0x7fffu + ((x >> 16) & 1u)) >> 16;
    return (unsigned short)r;
}

// ---------------- weight transpose: w[set][k][h][f] (fp32) -> bt[row=f'][col=k*256+h] (bf16)
// bt rows: [0,768) = w1 sets 0..2 ; [768,1536) = w2 sets 0..2
__global__ void k_wtrans(const float* __restrict__ w1, const float* __restrict__ w2,
                         unsigned short* __restrict__ bt) {
    __shared__ float tile[64][65];
    int id = blockIdx.x;
    int tf = id & 3; int th = (id >> 2) & 3;
    int rest = id >> 4;
    int k = rest % 3; rest /= 3;
    int set = rest % 3; int tensor = rest / 3;
    const float* src = tensor ? w2 : w1;
    const float* s = src + (((size_t)set * 3 + k) * 256 + th * 64) * 256 + tf * 64;
    int t = threadIdx.x;
    int fl = t & 63;
    int q = t >> 6;   // 0..3
#pragma unroll
    for (int i = 0; i < 16; ++i) {
        int hl = i * 4 + q;
        tile[hl][fl] = s[(size_t)hl * 256 + fl];
    }
    __syncthreads();
    size_t rowbase = (size_t)tensor * 768 + set * 256 + tf * 64;
    size_t colbase = (size_t)k * 256 + th * 64;
#pragma unroll
    for (int i = 0; i < 16; ++i) {
        int f2 = i * 4 + q;
        bt[(rowbase + f2) * KH + colbase + fl] = f2bf(tile[fl][f2]);
    }
}

// ---------------- duration cumsum + mel_len
__global__ void k_cumsum(const int* __restrict__ dur, int* __restrict__ cum,
                         float* __restrict__ mel_len_out) {
    int b = blockIdx.x; int l = threadIdx.x;
    __shared__ int sh[256];
    sh[l] = dur[b * 256 + l];
    for (int s = 1; s < 256; s <<= 1) {
        __syncthreads();
        int add = (l >= s) ? sh[l - s] : 0;
        __syncthreads();
        sh[l] += add;
    }
    __syncthreads();
    cum[b * 256 + l] = sh[l];
    if (l == 0) mel_len_out[b] = (float)sh[255];
}

// ---------------- embeddings + im2col(x), im2col(x_p), x_pe
__global__ void k_embed(const float* __restrict__ x, const float* __restrict__ pt,
                        const float* __restrict__ et, const float* __restrict__ pbins,
                        const float* __restrict__ ebins, const float* __restrict__ pemb,
                        const float* __restrict__ eemb,
                        unsigned short* __restrict__ im2x, unsigned short* __restrict__ im2xp,
                        float* __restrict__ xpe) {
    int p = blockIdx.x; int l = p & 255; int f = threadIdx.x;
    float ptv = pt[p], etv = et[p];
    int lo = 0, hi = 255;
    while (lo < hi) { int mid = (lo + hi) >> 1; if (pbins[mid] < ptv) lo = mid + 1; else hi = mid; }
    int pidx = lo;
    lo = 0; hi = 255;
    while (lo < hi) { int mid = (lo + hi) >> 1; if (ebins[mid] < etv) lo = mid + 1; else hi = mid; }
    int eidx = lo;
    float xv = x[(size_t)p * 256 + f];
    float xpv = xv + pemb[(size_t)pidx * 256 + f];
    float xpev = xpv + eemb[(size_t)eidx * 256 + f];
    xpe[(size_t)p * 256 + f] = xpev;
    unsigned short xb = f2bf(xv), xpb = f2bf(xpv);
    im2x [(size_t)p * KH + 256 + f] = xb;
    im2xp[(size_t)p * KH + 256 + f] = xpb;
    if (l < 255) { im2x[(size_t)(p + 1) * KH + f] = xb;  im2xp[(size_t)(p + 1) * KH + f] = xpb; }
    else         { im2x[(size_t)p * KH + 512 + f] = 0;   im2xp[(size_t)p * KH + 512 + f] = 0; }
    if (l > 0)   { im2x[(size_t)(p - 1) * KH + 512 + f] = xb; im2xp[(size_t)(p - 1) * KH + 512 + f] = xpb; }
    else         { im2x[(size_t)p * KH + f] = 0;         im2xp[(size_t)p * KH + f] = 0; }
}

// ---------------- grouped bf16 GEMM: C[p, ct*128+..] += A_ct (8192 x 768) * Bt rows (128 x 768)^T
struct PtrSet { const unsigned short* a[6]; };

__global__ __launch_bounds__(256) void k_gemm(PtrSet ps, const unsigned short* __restrict__ bt,
                                              float* __restrict__ c) {
    __shared__ unsigned short As[128 * 32];
    __shared__ unsigned short Bs[128 * 32];
    const unsigned short* A  = ps.a[blockIdx.y];
    const unsigned short* Bm = bt + (size_t)blockIdx.y * 128 * KH;
    const int rowBase = blockIdx.x * 128;
    const int colBase = blockIdx.y * 128;
    const int tid = threadIdx.x;
    const int lane = tid & 63;
    const int wv = tid >> 6;
    const int wr = wv >> 1, wc = wv & 1;

    f32x4 acc[4][4];
#pragma unroll
    for (int m = 0; m < 4; ++m)
#pragma unroll
        for (int n = 0; n < 4; ++n) acc[m][n] = (f32x4){0.f, 0.f, 0.f, 0.f};

    const int e0 = tid * 8;        const int r0 = e0 >> 5, c0 = e0 & 31;
    const int e1 = 2048 + tid * 8; const int r1 = e1 >> 5, c1 = e1 & 31;

    for (int kt = 0; kt < KH; kt += 32) {
        __builtin_amdgcn_global_load_lds(
            (const __attribute__((address_space(1))) unsigned int*)(A + (size_t)(rowBase + r0) * KH + kt + c0),
            (__attribute__((address_space(3))) unsigned int*)(As + e0), 16, 0, 0);
        __builtin_amdgcn_global_load_lds(
            (const __attribute__((address_space(1))) unsigned int*)(A + (size_t)(rowBase + r1) * KH + kt + c1),
            (__attribute__((address_space(3))) unsigned int*)(As + e1), 16, 0, 0);
        __builtin_amdgcn_global_load_lds(
            (const __attribute__((address_space(1))) unsigned int*)(Bm + (size_t)r0 * KH + kt + c0),
            (__attribute__((address_space(3))) unsigned int*)(Bs + e0), 16, 0, 0);
        __builtin_amdgcn_global_load_lds(
            (const __attribute__((address_space(1))) unsigned int*)(Bm + (size_t)r1 * KH + kt + c1),
            (__attribute__((address_space(3))) unsigned int*)(Bs + e1), 16, 0, 0);
        asm volatile("s_waitcnt vmcnt(0)" ::: "memory");
        __syncthreads();

        bf16x8 af[4], bfr[4];
        const int kof = (lane >> 4) * 8;
        const int rsel = lane & 15;
#pragma unroll
        for (int m = 0; m < 4; ++m)
            af[m] = *(const bf16x8*)(As + (size_t)(wr * 64 + m * 16 + rsel) * 32 + kof);
#pragma unroll
        for (int n = 0; n < 4; ++n)
            bfr[n] = *(const bf16x8*)(Bs + (size_t)(wc * 64 + n * 16 + rsel) * 32 + kof);
#pragma unroll
        for (int m = 0; m < 4; ++m)
#pragma unroll
            for (int n = 0; n < 4; ++n)
                acc[m][n] = __builtin_amdgcn_mfma_f32_16x16x32_bf16(af[m], bfr[n], acc[m][n], 0, 0, 0);
        __syncthreads();
    }

#pragma unroll
    for (int m = 0; m < 4; ++m)
#pragma unroll
        for (int n = 0; n < 4; ++n)
#pragma unroll
            for (int r = 0; r < 4; ++r) {
                int row = rowBase + wr * 64 + m * 16 + (lane >> 4) * 4 + r;
                int col = colBase + wc * 64 + n * 16 + (lane & 15);
                c[(size_t)row * KH + col] = acc[m][n][r];
            }
}

// ---------------- bias+relu+LN -> im2col(h) bf16 scatter
struct HPtrs { unsigned short* h[3]; };

__global__ void k_ln1(const float* __restrict__ conv, const float* __restrict__ b1,
                      const float* __restrict__ g1, const float* __restrict__ be1, HPtrs hp) {
    int p = blockIdx.x; int i = blockIdx.y; int f = threadIdx.x;
    int l = p & 255;
    float v = conv[(size_t)p * KH + i * 256 + f] + b1[i * 256 + f];
    v = fmaxf(v, 0.f);
    float s = v, s2 = v * v;
#pragma unroll
    for (int o = 32; o; o >>= 1) { s += __shfl_xor(s, o); s2 += __shfl_xor(s2, o); }
    __shared__ float red[8];
    int lane = f & 63, wv = f >> 6;
    if (lane == 0) { red[wv] = s; red[4 + wv] = s2; }
    __syncthreads();
    s  = red[0] + red[1] + red[2] + red[3];
    s2 = red[4] + red[5] + red[6] + red[7];
    float mean = s * (1.f / 256.f);
    float var = s2 * (1.f / 256.f) - mean * mean;
    float h = (v - mean) * rsqrtf(var + EPS_) * g1[i * 256 + f] + be1[i * 256 + f];
    unsigned short hb = f2bf(h);
    unsigned short* im = hp.h[i];
    im[(size_t)p * KH + 256 + f] = hb;
    if (l < 255) im[(size_t)(p + 1) * KH + f] = hb; else im[(size_t)p * KH + 512 + f] = 0;
    if (l > 0)   im[(size_t)(p - 1) * KH + 512 + f] = hb; else im[(size_t)p * KH + f] = 0;
}

// ---------------- bias+relu+LN+dot(wl)+mask -> predictions
__global__ void k_ln2(const float* __restrict__ conv, const float* __restrict__ b2,
                      const float* __restrict__ g2, const float* __restrict__ be2,
                      const float* __restrict__ wl, const float* __restrict__ bl,
                      const char* __restrict__ mask, float* __restrict__ outp) {
    int p = blockIdx.x; int i = blockIdx.y; int f = threadIdx.x;
    float v = conv[(size_t)p * KH + i * 256 + f] + b2[i * 256 + f];
    v = fmaxf(v, 0.f);
    float s = v, s2 = v * v;
#pragma unroll
    for (int o = 32; o; o >>= 1) { s += __shfl_xor(s, o); s2 += __shfl_xor(s2, o); }
    __shared__ float red[12];
    int lane = f & 63, wv = f >> 6;
    if (lane == 0) { red[wv] = s; red[4 + wv] = s2; }
    __syncthreads();
    s  = red[0] + red[1] + red[2] + red[3];
    s2 = red[4] + red[5] + red[6] + red[7];
    float mean = s * (1.f / 256.f);
    float var = s2 * (1.f / 256.f) - mean * mean;
    float h = (v - mean) * rsqrtf(var + EPS_) * g2[i * 256 + f] + be2[i * 256 + f];
    float d = h * wl[i * 256 + f];
#pragma unroll
    for (int o = 32; o; o >>= 1) d += __shfl_xor(d, o);
    if (lane == 0) red[8 + wv] = d;
    __syncthreads();
    if (f == 0) {
        float o = red[8] + red[9] + red[10] + red[11] + bl[i];
        if (mask[p]) o = 0.f;
        outp[(size_t)i * P_TOT + p] = o;
    }
}

// ---------------- length regulate gather + mel mask
__global__ void k_gather(const float* __restrict__ xpe, const int* __restrict__ cum,
                         float* __restrict__ out, float* __restrict__ maskout) {
    int bt = blockIdx.x; int b = bt >> 11; int t = bt & 2047; int f = threadIdx.x;
    const int* c = cum + b * 256;
    int lo = 0, hi = 256;
    while (lo < hi) { int mid = (lo + hi) >> 1; if (c[mid] <= t) lo = mid + 1; else hi = mid; }
    int mel = c[255];
    bool valid = t < mel;
    int idx = lo > 255 ? 255 : lo;
    float v = valid ? xpe[((size_t)b * 256 + idx) * 256 + f] : 0.f;
    out[(size_t)bt * 256 + f] = v;
    if (f == 0) maskout[bt] = valid ? 0.f : 1.f;
}

extern "C" void kernel_launch(void* const* d_in, const int* in_sizes, int n_in,
                              void* d_out, int out_size, void* d_ws, size_t ws_size,
                              hipStream_t stream) {
    const float* x     = (const float*)d_in[0];
    const float* pt    = (const float*)d_in[1];
    const float* et    = (const float*)d_in[2];
    const float* w1    = (const float*)d_in[3];
    const float* b1    = (const float*)d_in[4];
    const float* g1    = (const float*)d_in[5];
    const float* be1   = (const float*)d_in[6];
    const float* w2    = (const float*)d_in[7];
    const float* b2    = (const float*)d_in[8];
    const float* g2    = (const float*)d_in[9];
    const float* be2   = (const float*)d_in[10];
    const float* wl    = (const float*)d_in[11];
    const float* bl    = (const float*)d_in[12];
    const float* pbins = (const float*)d_in[13];
    const float* ebins = (const float*)d_in[14];
    const float* pemb  = (const float*)d_in[15];
    const float* eemb  = (const float*)d_in[16];
    const char*  mask  = (const char*)d_in[17];
    const int*   dur   = (const int*)d_in[18];

    char* ws = (char*)d_ws;
    // layout (bytes): im2x 12.58M | im2xp 12.58M | im2h2 12.58M | xpe 8.39M | bt 2.36M | cum 32K | convbuf 25.17M
    unsigned short* im2x  = (unsigned short*)(ws + 0);
    unsigned short* im2xp = (unsigned short*)(ws + 12582912);
    unsigned short* im2h2 = (unsigned short*)(ws + 25165824);
    float*          xpe   = (float*)(ws + 37748736);
    unsigned short* btall = (unsigned short*)(ws + 46137344);
    int*            cum   = (int*)(ws + 48496640);
    float*          convbuf = (float*)(ws + 48529408);
    // im2col(h) for preds 0,1 alias the (consumed) im2x / im2xp regions
    unsigned short* im2h0 = im2x;
    unsigned short* im2h1 = im2xp;

    float* out        = (float*)d_out;
    float* out_pred   = out + 16777216;           // log_dur | pitch | energy (8192 each)
    float* out_mellen = out + 16801792;
    float* out_mask   = out + 16801824;

    hipLaunchKernelGGL(k_wtrans, dim3(288), dim3(256), 0, stream, w1, w2, btall);
    hipLaunchKernelGGL(k_cumsum, dim3(32), dim3(256), 0, stream, dur, cum, out_mellen);
    hipLaunchKernelGGL(k_embed, dim3(8192), dim3(256), 0, stream,
                       x, pt, et, pbins, ebins, pemb, eemb, im2x, im2xp, xpe);

    PtrSet ps1;
    ps1.a[0] = ps1.a[1] = ps1.a[2] = ps1.a[3] = im2x;
    ps1.a[4] = ps1.a[5] = im2xp;
    hipLaunchKernelGGL(k_gemm, dim3(64, 6), dim3(256), 0, stream, ps1, btall, convbuf);

    HPtrs hp; hp.h[0] = im2h0; hp.h[1] = im2h1; hp.h[2] = im2h2;
    hipLaunchKernelGGL(k_ln1, dim3(8192, 3), dim3(256), 0, stream, convbuf, b1, g1, be1, hp);

    PtrSet ps2;
    ps2.a[0] = ps2.a[1] = im2h0;
    ps2.a[2] = ps2.a[3] = im2h1;
    ps2.a[4] = ps2.a[5] = im2h2;
    hipLaunchKernelGGL(k_gemm, dim3(64, 6), dim3(256), 0, stream, ps2, btall + (size_t)768 * KH, convbuf);

    hipLaunchKernelGGL(k_ln2, dim3(8192, 3), dim3(256), 0, stream,
                       convbuf, b2, g2, be2, wl, bl, mask, out_pred);
    hipLaunchKernelGGL(k_gather, dim3(65536), dim3(256), 0, stream, xpe, cum, out, out_mask);
}

// Round 2
// 130.135 us; speedup vs baseline: 1.3581x; 1.3581x over previous
//
#include <hip/hip_runtime.h>
#include <hip/hip_bf16.h>
#include <cstdint>

typedef float f32x4 __attribute__((ext_vector_type(4)));
typedef short bf16x8 __attribute__((ext_vector_type(8)));

#define P_TOT 8192      // B*L
#define KH 768          // K*H
#define EPS_ 1e-5f

__device__ __forceinline__ unsigned short f2bf(float f) {
    unsigned int x = __float_as_uint(f);
    unsigned int r = (x + 0x7fffu + ((x >> 16) & 1u)) >> 16;
    return (unsigned short)r;
}

// ---------------- weight transpose: w[set][k][h][f] (fp32) -> bt[row=f'][col=k*256+h] (bf16)
// bt rows: [0,768) = w1 sets 0..2 ; [768,1536) = w2 sets 0..2
__global__ void k_wtrans(const float* __restrict__ w1, const float* __restrict__ w2,
                         unsigned short* __restrict__ bt) {
    __shared__ float tile[64][65];
    int id = blockIdx.x;
    int tf = id & 3; int th = (id >> 2) & 3;
    int rest = id >> 4;
    int k = rest % 3; rest /= 3;
    int set = rest % 3; int tensor = rest / 3;
    const float* src = tensor ? w2 : w1;
    const float* s = src + (((size_t)set * 3 + k) * 256 + th * 64) * 256 + tf * 64;
    int t = threadIdx.x;
    int fl = t & 63;
    int q = t >> 6;   // 0..3
#pragma unroll
    for (int i = 0; i < 16; ++i) {
        int hl = i * 4 + q;
        tile[hl][fl] = s[(size_t)hl * 256 + fl];
    }
    __syncthreads();
    size_t rowbase = (size_t)tensor * 768 + set * 256 + tf * 64;
    size_t colbase = (size_t)k * 256 + th * 64;
#pragma unroll
    for (int i = 0; i < 16; ++i) {
        int f2 = i * 4 + q;
        bt[(rowbase + f2) * KH + colbase + fl] = f2bf(tile[fl][f2]);
    }
}

// ---------------- duration cumsum + mel_len
__global__ void k_cumsum(const int* __restrict__ dur, int* __restrict__ cum,
                         float* __restrict__ mel_len_out) {
    int b = blockIdx.x; int l = threadIdx.x;
    __shared__ int sh[256];
    sh[l] = dur[b * 256 + l];
    for (int s = 1; s < 256; s <<= 1) {
        __syncthreads();
        int add = (l >= s) ? sh[l - s] : 0;
        __syncthreads();
        sh[l] += add;
    }
    __syncthreads();
    cum[b * 256 + l] = sh[l];
    if (l == 0) mel_len_out[b] = (float)sh[255];
}

// ---------------- embeddings + im2col(x), im2col(x_p), x_pe
__global__ void k_embed(const float* __restrict__ x, const float* __restrict__ pt,
                        const float* __restrict__ et, const float* __restrict__ pbins,
                        const float* __restrict__ ebins, const float* __restrict__ pemb,
                        const float* __restrict__ eemb,
                        unsigned short* __restrict__ im2x, unsigned short* __restrict__ im2xp,
                        float* __restrict__ xpe) {
    int p = blockIdx.x; int l = p & 255; int f = threadIdx.x;
    float ptv = pt[p], etv = et[p];
    int lo = 0, hi = 255;
    while (lo < hi) { int mid = (lo + hi) >> 1; if (pbins[mid] < ptv) lo = mid + 1; else hi = mid; }
    int pidx = lo;
    lo = 0; hi = 255;
    while (lo < hi) { int mid = (lo + hi) >> 1; if (ebins[mid] < etv) lo = mid + 1; else hi = mid; }
    int eidx = lo;
    float xv = x[(size_t)p * 256 + f];
    float xpv = xv + pemb[(size_t)pidx * 256 + f];
    float xpev = xpv + eemb[(size_t)eidx * 256 + f];
    xpe[(size_t)p * 256 + f] = xpev;
    unsigned short xb = f2bf(xv), xpb = f2bf(xpv);
    im2x [(size_t)p * KH + 256 + f] = xb;
    im2xp[(size_t)p * KH + 256 + f] = xpb;
    if (l < 255) { im2x[(size_t)(p + 1) * KH + f] = xb;  im2xp[(size_t)(p + 1) * KH + f] = xpb; }
    else         { im2x[(size_t)p * KH + 512 + f] = 0;   im2xp[(size_t)p * KH + 512 + f] = 0; }
    if (l > 0)   { im2x[(size_t)(p - 1) * KH + 512 + f] = xb; im2xp[(size_t)(p - 1) * KH + 512 + f] = xpb; }
    else         { im2x[(size_t)p * KH + f] = 0;         im2xp[(size_t)p * KH + f] = 0; }
}

// ---------------- grouped bf16 GEMM: C[p, ct*128+..] += A_ct (8192 x 768) * Bt rows (128 x 768)^T
struct PtrSet { const unsigned short* a[6]; };

__global__ __launch_bounds__(256) void k_gemm(PtrSet ps, const unsigned short* __restrict__ bt,
                                              float* __restrict__ c) {
    __shared__ unsigned short As[128 * 32];
    __shared__ unsigned short Bs[128 * 32];
    const unsigned short* A  = ps.a[blockIdx.y];
    const unsigned short* Bm = bt + (size_t)blockIdx.y * 128 * KH;
    const int rowBase = blockIdx.x * 128;
    const int colBase = blockIdx.y * 128;
    const int tid = threadIdx.x;
    const int lane = tid & 63;
    const int wv = tid >> 6;
    const int wr = wv >> 1, wc = wv & 1;

    f32x4 acc[4][4];
#pragma unroll
    for (int m = 0; m < 4; ++m)
#pragma unroll
        for (int n = 0; n < 4; ++n) acc[m][n] = (f32x4){0.f, 0.f, 0.f, 0.f};

    const int e0 = tid * 8;        const int r0 = e0 >> 5, c0 = e0 & 31;
    const int e1 = 2048 + tid * 8; const int r1 = e1 >> 5, c1 = e1 & 31;

    for (int kt = 0; kt < KH; kt += 32) {
        __builtin_amdgcn_global_load_lds(
            (const __attribute__((address_space(1))) unsigned int*)(A + (size_t)(rowBase + r0) * KH + kt + c0),
            (__attribute__((address_space(3))) unsigned int*)(As + e0), 16, 0, 0);
        __builtin_amdgcn_global_load_lds(
            (const __attribute__((address_space(1))) unsigned int*)(A + (size_t)(rowBase + r1) * KH + kt + c1),
            (__attribute__((address_space(3))) unsigned int*)(As + e1), 16, 0, 0);
        __builtin_amdgcn_global_load_lds(
            (const __attribute__((address_space(1))) unsigned int*)(Bm + (size_t)r0 * KH + kt + c0),
            (__attribute__((address_space(3))) unsigned int*)(Bs + e0), 16, 0, 0);
        __builtin_amdgcn_global_load_lds(
            (const __attribute__((address_space(1))) unsigned int*)(Bm + (size_t)r1 * KH + kt + c1),
            (__attribute__((address_space(3))) unsigned int*)(Bs + e1), 16, 0, 0);
        asm volatile("s_waitcnt vmcnt(0)" ::: "memory");
        __syncthreads();

        bf16x8 af[4], bfr[4];
        const int kof = (lane >> 4) * 8;
        const int rsel = lane & 15;
#pragma unroll
        for (int m = 0; m < 4; ++m)
            af[m] = *(const bf16x8*)(As + (size_t)(wr * 64 + m * 16 + rsel) * 32 + kof);
#pragma unroll
        for (int n = 0; n < 4; ++n)
            bfr[n] = *(const bf16x8*)(Bs + (size_t)(wc * 64 + n * 16 + rsel) * 32 + kof);
#pragma unroll
        for (int m = 0; m < 4; ++m)
#pragma unroll
            for (int n = 0; n < 4; ++n)
                acc[m][n] = __builtin_amdgcn_mfma_f32_16x16x32_bf16(af[m], bfr[n], acc[m][n], 0, 0, 0);
        __syncthreads();
    }

#pragma unroll
    for (int m = 0; m < 4; ++m)
#pragma unroll
        for (int n = 0; n < 4; ++n)
#pragma unroll
            for (int r = 0; r < 4; ++r) {
                int row = rowBase + wr * 64 + m * 16 + (lane >> 4) * 4 + r;
                int col = colBase + wc * 64 + n * 16 + (lane & 15);
                c[(size_t)row * KH + col] = acc[m][n][r];
            }
}

// ---------------- bias+relu+LN -> im2col(h) bf16 scatter
struct HPtrs { unsigned short* h[3]; };

__global__ void k_ln1(const float* __restrict__ conv, const float* __restrict__ b1,
                      const float* __restrict__ g1, const float* __restrict__ be1, HPtrs hp) {
    int p = blockIdx.x; int i = blockIdx.y; int f = threadIdx.x;
    int l = p & 255;
    float v = conv[(size_t)p * KH + i * 256 + f] + b1[i * 256 + f];
    v = fmaxf(v, 0.f);
    float s = v, s2 = v * v;
#pragma unroll
    for (int o = 32; o; o >>= 1) { s += __shfl_xor(s, o); s2 += __shfl_xor(s2, o); }
    __shared__ float red[8];
    int lane = f & 63, wv = f >> 6;
    if (lane == 0) { red[wv] = s; red[4 + wv] = s2; }
    __syncthreads();
    s  = red[0] + red[1] + red[2] + red[3];
    s2 = red[4] + red[5] + red[6] + red[7];
    float mean = s * (1.f / 256.f);
    float var = s2 * (1.f / 256.f) - mean * mean;
    float h = (v - mean) * rsqrtf(var + EPS_) * g1[i * 256 + f] + be1[i * 256 + f];
    unsigned short hb = f2bf(h);
    unsigned short* im = hp.h[i];
    im[(size_t)p * KH + 256 + f] = hb;
    if (l < 255) im[(size_t)(p + 1) * KH + f] = hb; else im[(size_t)p * KH + 512 + f] = 0;
    if (l > 0)   im[(size_t)(p - 1) * KH + 512 + f] = hb; else im[(size_t)p * KH + f] = 0;
}

// ---------------- bias+relu+LN+dot(wl)+mask -> predictions
__global__ void k_ln2(const float* __restrict__ conv, const float* __restrict__ b2,
                      const float* __restrict__ g2, const float* __restrict__ be2,
                      const float* __restrict__ wl, const float* __restrict__ bl,
                      const char* __restrict__ mask, float* __restrict__ outp) {
    int p = blockIdx.x; int i = blockIdx.y; int f = threadIdx.x;
    float v = conv[(size_t)p * KH + i * 256 + f] + b2[i * 256 + f];
    v = fmaxf(v, 0.f);
    float s = v, s2 = v * v;
#pragma unroll
    for (int o = 32; o; o >>= 1) { s += __shfl_xor(s, o); s2 += __shfl_xor(s2, o); }
    __shared__ float red[12];
    int lane = f & 63, wv = f >> 6;
    if (lane == 0) { red[wv] = s; red[4 + wv] = s2; }
    __syncthreads();
    s  = red[0] + red[1] + red[2] + red[3];
    s2 = red[4] + red[5] + red[6] + red[7];
    float mean = s * (1.f / 256.f);
    float var = s2 * (1.f / 256.f) - mean * mean;
    float h = (v - mean) * rsqrtf(var + EPS_) * g2[i * 256 + f] + be2[i * 256 + f];
    float d = h * wl[i * 256 + f];
#pragma unroll
    for (int o = 32; o; o >>= 1) d += __shfl_xor(d, o);
    if (lane == 0) red[8 + wv] = d;
    __syncthreads();
    if (f == 0) {
        float o = red[8] + red[9] + red[10] + red[11] + bl[i];
        if (mask[p]) o = 0.f;
        outp[(size_t)i * P_TOT + p] = o;
    }
}

// ---------------- length regulate gather + mel mask (LDS cumsum + float4 rows)
// grid: (2048/32, 32) ; block 256. Each block: one batch, 32 mel rows.
__global__ __launch_bounds__(256) void k_gather(const float* __restrict__ xpe,
                                                const int* __restrict__ cum,
                                                float* __restrict__ out,
                                                float* __restrict__ maskout) {
    int b = blockIdx.y;
    int t0 = blockIdx.x * 32;
    __shared__ int sc[256];
    int tid = threadIdx.x;
    sc[tid] = cum[b * 256 + tid];
    __syncthreads();
    int mel = sc[255];
    int wv = tid >> 6, lane = tid & 63;
#pragma unroll
    for (int it = 0; it < 8; ++it) {
        int t = t0 + it * 4 + wv;
        int lo = 0, hi = 256;
        while (lo < hi) { int mid = (lo + hi) >> 1; if (sc[mid] <= t) lo = mid + 1; else hi = mid; }
        bool valid = t < mel;
        int idx = lo > 255 ? 255 : lo;
        f32x4 v = (f32x4){0.f, 0.f, 0.f, 0.f};
        if (valid) v = *(const f32x4*)(xpe + ((size_t)(b * 256 + idx)) * 256 + lane * 4);
        *(f32x4*)(out + ((size_t)(b * 2048 + t)) * 256 + lane * 4) = v;
        if (lane == 0) maskout[b * 2048 + t] = valid ? 0.f : 1.f;
    }
}

extern "C" void kernel_launch(void* const* d_in, const int* in_sizes, int n_in,
                              void* d_out, int out_size, void* d_ws, size_t ws_size,
                              hipStream_t stream) {
    const float* x     = (const float*)d_in[0];
    const float* pt    = (const float*)d_in[1];
    const float* et    = (const float*)d_in[2];
    const float* w1    = (const float*)d_in[3];
    const float* b1    = (const float*)d_in[4];
    const float* g1    = (const float*)d_in[5];
    const float* be1   = (const float*)d_in[6];
    const float* w2    = (const float*)d_in[7];
    const float* b2    = (const float*)d_in[8];
    const float* g2    = (const float*)d_in[9];
    const float* be2   = (const float*)d_in[10];
    const float* wl    = (const float*)d_in[11];
    const float* bl    = (const float*)d_in[12];
    const float* pbins = (const float*)d_in[13];
    const float* ebins = (const float*)d_in[14];
    const float* pemb  = (const float*)d_in[15];
    const float* eemb  = (const float*)d_in[16];
    const char*  mask  = (const char*)d_in[17];
    const int*   dur   = (const int*)d_in[18];

    char* ws = (char*)d_ws;
    unsigned short* im2x  = (unsigned short*)(ws + 0);
    unsigned short* im2xp = (unsigned short*)(ws + 12582912);
    unsigned short* im2h2 = (unsigned short*)(ws + 25165824);
    float*          xpe   = (float*)(ws + 37748736);
    unsigned short* btall = (unsigned short*)(ws + 46137344);
    int*            cum   = (int*)(ws + 48496640);
    float*          convbuf = (float*)(ws + 48529408);
    unsigned short* im2h0 = im2x;
    unsigned short* im2h1 = im2xp;

    float* out        = (float*)d_out;
    float* out_pred   = out + 16777216;           // log_dur | pitch | energy (8192 each)
    float* out_mellen = out + 16801792;
    float* out_mask   = out + 16801824;

    hipLaunchKernelGGL(k_wtrans, dim3(288), dim3(256), 0, stream, w1, w2, btall);
    hipLaunchKernelGGL(k_cumsum, dim3(32), dim3(256), 0, stream, dur, cum, out_mellen);
    hipLaunchKernelGGL(k_embed, dim3(8192), dim3(256), 0, stream,
                       x, pt, et, pbins, ebins, pemb, eemb, im2x, im2xp, xpe);

    PtrSet ps1;
    ps1.a[0] = ps1.a[1] = ps1.a[2] = ps1.a[3] = im2x;
    ps1.a[4] = ps1.a[5] = im2xp;
    hipLaunchKernelGGL(k_gemm, dim3(64, 6), dim3(256), 0, stream, ps1, btall, convbuf);

    HPtrs hp; hp.h[0] = im2h0; hp.h[1] = im2h1; hp.h[2] = im2h2;
    hipLaunchKernelGGL(k_ln1, dim3(8192, 3), dim3(256), 0, stream, convbuf, b1, g1, be1, hp);

    PtrSet ps2;
    ps2.a[0] = ps2.a[1] = im2h0;
    ps2.a[2] = ps2.a[3] = im2h1;
    ps2.a[4] = ps2.a[5] = im2h2;
    hipLaunchKernelGGL(k_gemm, dim3(64, 6), dim3(256), 0, stream, ps2, btall + (size_t)768 * KH, convbuf);

    hipLaunchKernelGGL(k_ln2, dim3(8192, 3), dim3(256), 0, stream,
                       convbuf, b2, g2, be2, wl, bl, mask, out_pred);
    hipLaunchKernelGGL(k_gather, dim3(64, 32), dim3(256), 0, stream, xpe, cum, out, out_mask);
}

// Round 3
// 103.692 us; speedup vs baseline: 1.7045x; 1.2550x over previous
//
#include <hip/hip_runtime.h>
#include <hip/hip_bf16.h>
#include <cstdint>

typedef float f32x4 __attribute__((ext_vector_type(4)));
typedef short bf16x8 __attribute__((ext_vector_type(8)));

#define P_TOT 8192      // B*L
#define KH 768          // K*H
#define EPS_ 1e-5f

__device__ __forceinline__ unsigned short f2bf(float f) {
    unsigned int x = __float_as_uint(f);
    unsigned int r = (x + 0x7fffu + ((x >> 16) & 1u)) >> 16;
    return (unsigned short)r;
}

// ---------------- weight transpose: w[set][k][h][f] (fp32) -> bt[row=f'][col=k*256+h] (bf16)
// bt rows: [0,768) = w1 sets 0..2 ; [768,1536) = w2 sets 0..2
__global__ void k_wtrans(const float* __restrict__ w1, const float* __restrict__ w2,
                         unsigned short* __restrict__ bt) {
    __shared__ float tile[64][65];
    int id = blockIdx.x;
    int tf = id & 3; int th = (id >> 2) & 3;
    int rest = id >> 4;
    int k = rest % 3; rest /= 3;
    int set = rest % 3; int tensor = rest / 3;
    const float* src = tensor ? w2 : w1;
    const float* s = src + (((size_t)set * 3 + k) * 256 + th * 64) * 256 + tf * 64;
    int t = threadIdx.x;
    int fl = t & 63;
    int q = t >> 6;   // 0..3
#pragma unroll
    for (int i = 0; i < 16; ++i) {
        int hl = i * 4 + q;
        tile[hl][fl] = s[(size_t)hl * 256 + fl];
    }
    __syncthreads();
    size_t rowbase = (size_t)tensor * 768 + set * 256 + tf * 64;
    size_t colbase = (size_t)k * 256 + th * 64;
#pragma unroll
    for (int i = 0; i < 16; ++i) {
        int f2 = i * 4 + q;
        bt[(rowbase + f2) * KH + colbase + fl] = f2bf(tile[fl][f2]);
    }
}

// ---------------- duration cumsum + mel_len
__global__ void k_cumsum(const int* __restrict__ dur, int* __restrict__ cum,
                         float* __restrict__ mel_len_out) {
    int b = blockIdx.x; int l = threadIdx.x;
    __shared__ int sh[256];
    sh[l] = dur[b * 256 + l];
    for (int s = 1; s < 256; s <<= 1) {
        __syncthreads();
        int add = (l >= s) ? sh[l - s] : 0;
        __syncthreads();
        sh[l] += add;
    }
    __syncthreads();
    cum[b * 256 + l] = sh[l];
    if (l == 0) mel_len_out[b] = (float)sh[255];
}

// ---------------- embeddings + im2col(x), im2col(x_p), x_pe
__global__ void k_embed(const float* __restrict__ x, const float* __restrict__ pt,
                        const float* __restrict__ et, const float* __restrict__ pbins,
                        const float* __restrict__ ebins, const float* __restrict__ pemb,
                        const float* __restrict__ eemb,
                        unsigned short* __restrict__ im2x, unsigned short* __restrict__ im2xp,
                        float* __restrict__ xpe) {
    int p = blockIdx.x; int l = p & 255; int f = threadIdx.x;
    float ptv = pt[p], etv = et[p];
    int lo = 0, hi = 255;
    while (lo < hi) { int mid = (lo + hi) >> 1; if (pbins[mid] < ptv) lo = mid + 1; else hi = mid; }
    int pidx = lo;
    lo = 0; hi = 255;
    while (lo < hi) { int mid = (lo + hi) >> 1; if (ebins[mid] < etv) lo = mid + 1; else hi = mid; }
    int eidx = lo;
    float xv = x[(size_t)p * 256 + f];
    float xpv = xv + pemb[(size_t)pidx * 256 + f];
    float xpev = xpv + eemb[(size_t)eidx * 256 + f];
    xpe[(size_t)p * 256 + f] = xpev;
    unsigned short xb = f2bf(xv), xpb = f2bf(xpv);
    im2x [(size_t)p * KH + 256 + f] = xb;
    im2xp[(size_t)p * KH + 256 + f] = xpb;
    if (l < 255) { im2x[(size_t)(p + 1) * KH + f] = xb;  im2xp[(size_t)(p + 1) * KH + f] = xpb; }
    else         { im2x[(size_t)p * KH + 512 + f] = 0;   im2xp[(size_t)p * KH + 512 + f] = 0; }
    if (l > 0)   { im2x[(size_t)(p - 1) * KH + 512 + f] = xb; im2xp[(size_t)(p - 1) * KH + 512 + f] = xpb; }
    else         { im2x[(size_t)p * KH + f] = 0;         im2xp[(size_t)p * KH + f] = 0; }
}

// ================= fused conv GEMM (64x256 tile) + bias + relu + LN =================
// Common core: A (P_TOT x 768) bf16, B rows 256 x 768 bf16 (B^T form), block computes
// rows [rowBase,rowBase+64) x cols [0,256). 4 waves, wave wc owns cols [wc*64, wc*64+64).

// kernel A: LN -> bf16 im2col scatter into hout
__global__ __launch_bounds__(256) void k_conv_ln1(
        const unsigned short* __restrict__ im2x, const unsigned short* __restrict__ im2xp,
        const unsigned short* __restrict__ bt,
        const float* __restrict__ b1, const float* __restrict__ g1, const float* __restrict__ be1,
        unsigned short* __restrict__ h0, unsigned short* __restrict__ h1, unsigned short* __restrict__ h2) {
    __shared__ unsigned short As[64 * 32];
    __shared__ unsigned short Bs[256 * 32];
    __shared__ float2 red[4][64];

    const int pred = blockIdx.y;
    const unsigned short* A  = (pred < 2) ? im2x : im2xp;
    const unsigned short* Bm = bt + (size_t)pred * 256 * KH;
    unsigned short* hout = (pred == 0) ? h0 : (pred == 1) ? h1 : h2;

    const int rowBase = blockIdx.x * 64;
    const int tid = threadIdx.x;
    const int lane = tid & 63;
    const int wc = tid >> 6;          // col-wave 0..3
    const int rsel = lane & 15;
    const int lhi = lane >> 4;        // 0..3
    const int ar = tid >> 2;          // staging row 0..63
    const int ac = (tid & 3) * 8;     // staging col

    f32x4 acc[4][4];
#pragma unroll
    for (int m = 0; m < 4; ++m)
#pragma unroll
        for (int n = 0; n < 4; ++n) acc[m][n] = (f32x4){0.f, 0.f, 0.f, 0.f};

    for (int kt = 0; kt < KH; kt += 32) {
        __builtin_amdgcn_global_load_lds(
            (const __attribute__((address_space(1))) unsigned int*)(A + (size_t)(rowBase + ar) * KH + kt + ac),
            (__attribute__((address_space(3))) unsigned int*)(As + tid * 8), 16, 0, 0);
#pragma unroll
        for (int j = 0; j < 4; ++j)
            __builtin_amdgcn_global_load_lds(
                (const __attribute__((address_space(1))) unsigned int*)(Bm + (size_t)(j * 64 + ar) * KH + kt + ac),
                (__attribute__((address_space(3))) unsigned int*)(Bs + j * 2048 + tid * 8), 16, 0, 0);
        asm volatile("s_waitcnt vmcnt(0)" ::: "memory");
        __syncthreads();

        bf16x8 af[4], bfr[4];
        const int kof = lhi * 8;
#pragma unroll
        for (int m = 0; m < 4; ++m)
            af[m] = *(const bf16x8*)(As + (size_t)(m * 16 + rsel) * 32 + kof);
#pragma unroll
        for (int n = 0; n < 4; ++n)
            bfr[n] = *(const bf16x8*)(Bs + (size_t)(wc * 64 + n * 16 + rsel) * 32 + kof);
#pragma unroll
        for (int m = 0; m < 4; ++m)
#pragma unroll
            for (int n = 0; n < 4; ++n)
                acc[m][n] = __builtin_amdgcn_mfma_f32_16x16x32_bf16(af[m], bfr[n], acc[m][n], 0, 0, 0);
        __syncthreads();
    }

    // per-thread column params
    float bcol[4], gcol[4], becol[4];
#pragma unroll
    for (int n = 0; n < 4; ++n) {
        int c = wc * 64 + n * 16 + rsel;
        bcol[n] = b1[pred * 256 + c];
        gcol[n] = g1[pred * 256 + c];
        becol[n] = be1[pred * 256 + c];
    }

    // row stats: sum / sumsq over this wave's 64 cols, then cross-wave
#pragma unroll
    for (int m = 0; m < 4; ++m)
#pragma unroll
        for (int r = 0; r < 4; ++r) {
            float s = 0.f, s2 = 0.f;
#pragma unroll
            for (int n = 0; n < 4; ++n) {
                float v = fmaxf(acc[m][n][r] + bcol[n], 0.f);
                s += v; s2 += v * v;
            }
#pragma unroll
            for (int o = 1; o < 16; o <<= 1) { s += __shfl_xor(s, o); s2 += __shfl_xor(s2, o); }
            if (rsel == 0) red[wc][m * 16 + lhi * 4 + r] = make_float2(s, s2);
        }
    __syncthreads();
    if (tid < 64) {
        float2 a0 = red[0][tid], a1 = red[1][tid], a2 = red[2][tid], a3 = red[3][tid];
        red[0][tid] = make_float2(a0.x + a1.x + a2.x + a3.x, a0.y + a1.y + a2.y + a3.y);
    }
    __syncthreads();

#pragma unroll
    for (int m = 0; m < 4; ++m)
#pragma unroll
        for (int r = 0; r < 4; ++r) {
            int rl = m * 16 + lhi * 4 + r;
            float2 t = red[0][rl];
            float mean = t.x * (1.f / 256.f);
            float var = t.y * (1.f / 256.f) - mean * mean;
            float inv = rsqrtf(var + EPS_);
            int p = rowBase + rl;
            int l = p & 255;
#pragma unroll
            for (int n = 0; n < 4; ++n) {
                float v = fmaxf(acc[m][n][r] + bcol[n], 0.f);
                float h = (v - mean) * inv * gcol[n] + becol[n];
                unsigned short hb = f2bf(h);
                int c = wc * 64 + n * 16 + rsel;
                hout[(size_t)p * KH + 256 + c] = hb;
                if (l < 255) hout[(size_t)(p + 1) * KH + c] = hb;
                else         hout[(size_t)p * KH + 512 + c] = 0;
                if (l > 0)   hout[(size_t)(p - 1) * KH + 512 + c] = hb;
                else         hout[(size_t)p * KH + c] = 0;
            }
        }
}

// kernel B: LN -> dot(wl) + bias + mask -> predictions
__global__ __launch_bounds__(256) void k_conv_ln2(
        const unsigned short* __restrict__ h0, const unsigned short* __restrict__ h1,
        const unsigned short* __restrict__ h2, const unsigned short* __restrict__ bt,
        const float* __restrict__ b2, const float* __restrict__ g2, const float* __restrict__ be2,
        const float* __restrict__ wl, const float* __restrict__ bl,
        const char* __restrict__ mask, float* __restrict__ outp) {
    __shared__ unsigned short As[64 * 32];
    __shared__ unsigned short Bs[256 * 32];
    __shared__ float2 red[4][64];
    __shared__ float red2[4][64];

    const int pred = blockIdx.y;
    const unsigned short* A  = (pred == 0) ? h0 : (pred == 1) ? h1 : h2;
    const unsigned short* Bm = bt + (size_t)(768 + pred * 256) * KH;

    const int rowBase = blockIdx.x * 64;
    const int tid = threadIdx.x;
    const int lane = tid & 63;
    const int wc = tid >> 6;
    const int rsel = lane & 15;
    const int lhi = lane >> 4;
    const int ar = tid >> 2;
    const int ac = (tid & 3) * 8;

    f32x4 acc[4][4];
#pragma unroll
    for (int m = 0; m < 4; ++m)
#pragma unroll
        for (int n = 0; n < 4; ++n) acc[m][n] = (f32x4){0.f, 0.f, 0.f, 0.f};

    for (int kt = 0; kt < KH; kt += 32) {
        __builtin_amdgcn_global_load_lds(
            (const __attribute__((address_space(1))) unsigned int*)(A + (size_t)(rowBase + ar) * KH + kt + ac),
            (__attribute__((address_space(3))) unsigned int*)(As + tid * 8), 16, 0, 0);
#pragma unroll
        for (int j = 0; j < 4; ++j)
            __builtin_amdgcn_global_load_lds(
                (const __attribute__((address_space(1))) unsigned int*)(Bm + (size_t)(j * 64 + ar) * KH + kt + ac),
                (__attribute__((address_space(3))) unsigned int*)(Bs + j * 2048 + tid * 8), 16, 0, 0);
        asm volatile("s_waitcnt vmcnt(0)" ::: "memory");
        __syncthreads();

        bf16x8 af[4], bfr[4];
        const int kof = lhi * 8;
#pragma unroll
        for (int m = 0; m < 4; ++m)
            af[m] = *(const bf16x8*)(As + (size_t)(m * 16 + rsel) * 32 + kof);
#pragma unroll
        for (int n = 0; n < 4; ++n)
            bfr[n] = *(const bf16x8*)(Bs + (size_t)(wc * 64 + n * 16 + rsel) * 32 + kof);
#pragma unroll
        for (int m = 0; m < 4; ++m)
#pragma unroll
            for (int n = 0; n < 4; ++n)
                acc[m][n] = __builtin_amdgcn_mfma_f32_16x16x32_bf16(af[m], bfr[n], acc[m][n], 0, 0, 0);
        __syncthreads();
    }

    float bcol[4], gcol[4], becol[4], wcol[4];
#pragma unroll
    for (int n = 0; n < 4; ++n) {
        int c = wc * 64 + n * 16 + rsel;
        bcol[n] = b2[pred * 256 + c];
        gcol[n] = g2[pred * 256 + c];
        becol[n] = be2[pred * 256 + c];
        wcol[n] = wl[pred * 256 + c];
    }

#pragma unroll
    for (int m = 0; m < 4; ++m)
#pragma unroll
        for (int r = 0; r < 4; ++r) {
            float s = 0.f, s2 = 0.f;
#pragma unroll
            for (int n = 0; n < 4; ++n) {
                float v = fmaxf(acc[m][n][r] + bcol[n], 0.f);
                s += v; s2 += v * v;
            }
#pragma unroll
            for (int o = 1; o < 16; o <<= 1) { s += __shfl_xor(s, o); s2 += __shfl_xor(s2, o); }
            if (rsel == 0) red[wc][m * 16 + lhi * 4 + r] = make_float2(s, s2);
        }
    __syncthreads();
    if (tid < 64) {
        float2 a0 = red[0][tid], a1 = red[1][tid], a2 = red[2][tid], a3 = red[3][tid];
        red[0][tid] = make_float2(a0.x + a1.x + a2.x + a3.x, a0.y + a1.y + a2.y + a3.y);
    }
    __syncthreads();

#pragma unroll
    for (int m = 0; m < 4; ++m)
#pragma unroll
        for (int r = 0; r < 4; ++r) {
            int rl = m * 16 + lhi * 4 + r;
            float2 t = red[0][rl];
            float mean = t.x * (1.f / 256.f);
            float var = t.y * (1.f / 256.f) - mean * mean;
            float inv = rsqrtf(var + EPS_);
            float d = 0.f;
#pragma unroll
            for (int n = 0; n < 4; ++n) {
                float v = fmaxf(acc[m][n][r] + bcol[n], 0.f);
                float h = (v - mean) * inv * gcol[n] + becol[n];
                d += h * wcol[n];
            }
#pragma unroll
            for (int o = 1; o < 16; o <<= 1) d += __shfl_xor(d, o);
            if (rsel == 0) red2[wc][rl] = d;
        }
    __syncthreads();
    if (tid < 64) {
        int p = rowBase + tid;
        float o = red2[0][tid] + red2[1][tid] + red2[2][tid] + red2[3][tid] + bl[pred];
        if (mask[p]) o = 0.f;
        outp[(size_t)pred * P_TOT + p] = o;
    }
}

// ---------------- length regulate gather + mel mask (LDS cumsum + float4 rows)
__global__ __launch_bounds__(256) void k_gather(const float* __restrict__ xpe,
                                                const int* __restrict__ cum,
                                                float* __restrict__ out,
                                                float* __restrict__ maskout) {
    int b = blockIdx.y;
    int t0 = blockIdx.x * 32;
    __shared__ int sc[256];
    int tid = threadIdx.x;
    sc[tid] = cum[b * 256 + tid];
    __syncthreads();
    int mel = sc[255];
    int wv = tid >> 6, lane = tid & 63;
#pragma unroll
    for (int it = 0; it < 8; ++it) {
        int t = t0 + it * 4 + wv;
        int lo = 0, hi = 256;
        while (lo < hi) { int mid = (lo + hi) >> 1; if (sc[mid] <= t) lo = mid + 1; else hi = mid; }
        bool valid = t < mel;
        int idx = lo > 255 ? 255 : lo;
        f32x4 v = (f32x4){0.f, 0.f, 0.f, 0.f};
        if (valid) v = *(const f32x4*)(xpe + ((size_t)(b * 256 + idx)) * 256 + lane * 4);
        *(f32x4*)(out + ((size_t)(b * 2048 + t)) * 256 + lane * 4) = v;
        if (lane == 0) maskout[b * 2048 + t] = valid ? 0.f : 1.f;
    }
}

extern "C" void kernel_launch(void* const* d_in, const int* in_sizes, int n_in,
                              void* d_out, int out_size, void* d_ws, size_t ws_size,
                              hipStream_t stream) {
    const float* x     = (const float*)d_in[0];
    const float* pt    = (const float*)d_in[1];
    const float* et    = (const float*)d_in[2];
    const float* w1    = (const float*)d_in[3];
    const float* b1    = (const float*)d_in[4];
    const float* g1    = (const float*)d_in[5];
    const float* be1   = (const float*)d_in[6];
    const float* w2    = (const float*)d_in[7];
    const float* b2    = (const float*)d_in[8];
    const float* g2    = (const float*)d_in[9];
    const float* be2   = (const float*)d_in[10];
    const float* wl    = (const float*)d_in[11];
    const float* bl    = (const float*)d_in[12];
    const float* pbins = (const float*)d_in[13];
    const float* ebins = (const float*)d_in[14];
    const float* pemb  = (const float*)d_in[15];
    const float* eemb  = (const float*)d_in[16];
    const char*  mask  = (const char*)d_in[17];
    const int*   dur   = (const int*)d_in[18];

    char* ws = (char*)d_ws;
    unsigned short* im2x  = (unsigned short*)(ws + 0);
    unsigned short* im2xp = (unsigned short*)(ws + 12582912);
    unsigned short* im2h0 = (unsigned short*)(ws + 25165824);
    unsigned short* im2h1 = (unsigned short*)(ws + 37748736);
    unsigned short* im2h2 = (unsigned short*)(ws + 50331648);
    float*          xpe   = (float*)(ws + 62914560);
    unsigned short* btall = (unsigned short*)(ws + 71303168);
    int*            cum   = (int*)(ws + 73662464);

    float* out        = (float*)d_out;
    float* out_pred   = out + 16777216;           // log_dur | pitch | energy (8192 each)
    float* out_mellen = out + 16801792;
    float* out_mask   = out + 16801824;

    hipLaunchKernelGGL(k_wtrans, dim3(288), dim3(256), 0, stream, w1, w2, btall);
    hipLaunchKernelGGL(k_cumsum, dim3(32), dim3(256), 0, stream, dur, cum, out_mellen);
    hipLaunchKernelGGL(k_embed, dim3(8192), dim3(256), 0, stream,
                       x, pt, et, pbins, ebins, pemb, eemb, im2x, im2xp, xpe);

    hipLaunchKernelGGL(k_conv_ln1, dim3(128, 3), dim3(256), 0, stream,
                       im2x, im2xp, btall, b1, g1, be1, im2h0, im2h1, im2h2);
    hipLaunchKernelGGL(k_conv_ln2, dim3(128, 3), dim3(256), 0, stream,
                       im2h0, im2h1, im2h2, btall, b2, g2, be2, wl, bl, mask, out_pred);

    hipLaunchKernelGGL(k_gather, dim3(64, 32), dim3(256), 0, stream, xpe, cum, out, out_mask);
}

// Round 4
// 102.467 us; speedup vs baseline: 1.7249x; 1.0120x over previous
//
#include <hip/hip_runtime.h>
#include <hip/hip_bf16.h>
#include <cstdint>

typedef float f32x4 __attribute__((ext_vector_type(4)));
typedef short bf16x8 __attribute__((ext_vector_type(8)));

#define P_TOT 8192      // B*L
#define KH 768          // K*H (GEMM K-dim)
#define PADL 258        // padded sequence length (zero row before & after)
#define EPS_ 1e-5f

__device__ __forceinline__ unsigned short f2bf(float f) {
    unsigned int x = __float_as_uint(f);
    unsigned int r = (x + 0x7fffu + ((x >> 16) & 1u)) >> 16;
    return (unsigned short)r;
}

// ---------------- weight transpose: w[set][k][h][f] (fp32) -> bt[row=f'][col=k*256+h] (bf16)
__global__ void k_wtrans(const float* __restrict__ w1, const float* __restrict__ w2,
                         unsigned short* __restrict__ bt) {
    __shared__ float tile[64][65];
    int id = blockIdx.x;
    int tf = id & 3; int th = (id >> 2) & 3;
    int rest = id >> 4;
    int k = rest % 3; rest /= 3;
    int set = rest % 3; int tensor = rest / 3;
    const float* src = tensor ? w2 : w1;
    const float* s = src + (((size_t)set * 3 + k) * 256 + th * 64) * 256 + tf * 64;
    int t = threadIdx.x;
    int fl = t & 63;
    int q = t >> 6;
#pragma unroll
    for (int i = 0; i < 16; ++i) {
        int hl = i * 4 + q;
        tile[hl][fl] = s[(size_t)hl * 256 + fl];
    }
    __syncthreads();
    size_t rowbase = (size_t)tensor * 768 + set * 256 + tf * 64;
    size_t colbase = (size_t)k * 256 + th * 64;
#pragma unroll
    for (int i = 0; i < 16; ++i) {
        int f2 = i * 4 + q;
        bt[(rowbase + f2) * KH + colbase + fl] = f2bf(tile[fl][f2]);
    }
}

// ---------------- duration cumsum + mel_len
__global__ void k_cumsum(const int* __restrict__ dur, int* __restrict__ cum,
                         float* __restrict__ mel_len_out) {
    int b = blockIdx.x; int l = threadIdx.x;
    __shared__ int sh[256];
    sh[l] = dur[b * 256 + l];
    for (int s = 1; s < 256; s <<= 1) {
        __syncthreads();
        int add = (l >= s) ? sh[l - s] : 0;
        __syncthreads();
        sh[l] += add;
    }
    __syncthreads();
    cum[b * 256 + l] = sh[l];
    if (l == 0) mel_len_out[b] = (float)sh[255];
}

// ---------------- embeddings -> plain padded bf16 x, x_p + fp32 xpe
__global__ void k_embed(const float* __restrict__ x, const float* __restrict__ pt,
                        const float* __restrict__ et, const float* __restrict__ pbins,
                        const float* __restrict__ ebins, const float* __restrict__ pemb,
                        const float* __restrict__ eemb,
                        unsigned short* __restrict__ xplain, unsigned short* __restrict__ xpplain,
                        float* __restrict__ xpe) {
    int p = blockIdx.x; int b = p >> 8; int l = p & 255; int f = threadIdx.x;
    float ptv = pt[p], etv = et[p];
    int lo = 0, hi = 255;
    while (lo < hi) { int mid = (lo + hi) >> 1; if (pbins[mid] < ptv) lo = mid + 1; else hi = mid; }
    int pidx = lo;
    lo = 0; hi = 255;
    while (lo < hi) { int mid = (lo + hi) >> 1; if (ebins[mid] < etv) lo = mid + 1; else hi = mid; }
    int eidx = lo;
    float xv = x[(size_t)p * 256 + f];
    float xpv = xv + pemb[(size_t)pidx * 256 + f];
    float xpev = xpv + eemb[(size_t)eidx * 256 + f];
    xpe[(size_t)p * 256 + f] = xpev;
    size_t row = (size_t)b * PADL + 1 + l;
    xplain [row * 256 + f] = f2bf(xv);
    xpplain[row * 256 + f] = f2bf(xpv);
    if (l == 0)   { xplain[((size_t)b * PADL) * 256 + f] = 0;       xpplain[((size_t)b * PADL) * 256 + f] = 0; }
    if (l == 255) { xplain[((size_t)b * PADL + 257) * 256 + f] = 0; xpplain[((size_t)b * PADL + 257) * 256 + f] = 0; }
}

// ================= fused conv GEMM core helpers =================
// A: plain padded bf16 [B][PADL][256]. browPad = b*PADL + l0 ; step kt: tap=kt>>8, hc=kt&255.
// Stage A 64x32 (rows browPad+tap+ar) and B 256x32 into As/Bs.
__device__ __forceinline__ void stage_tile(const unsigned short* __restrict__ A,
                                           const unsigned short* __restrict__ Bm,
                                           int browPad, int kt,
                                           unsigned short* As, unsigned short* Bs, int tid) {
    const int tap = kt >> 8, hc = kt & 255;
    const int ar = tid >> 2;
    const int ac = (tid & 3) * 8;
    __builtin_amdgcn_global_load_lds(
        (const __attribute__((address_space(1))) unsigned int*)(A + (size_t)(browPad + tap + ar) * 256 + hc + ac),
        (__attribute__((address_space(3))) unsigned int*)(As + tid * 8), 16, 0, 0);
#pragma unroll
    for (int j = 0; j < 4; ++j)
        __builtin_amdgcn_global_load_lds(
            (const __attribute__((address_space(1))) unsigned int*)(Bm + (size_t)(j * 64 + ar) * KH + kt + ac),
            (__attribute__((address_space(3))) unsigned int*)(Bs + j * 2048 + tid * 8), 16, 0, 0);
}

__device__ __forceinline__ void compute_tile(const unsigned short* As, const unsigned short* Bs,
                                             int lane, int wc, f32x4 acc[4][4]) {
    const int rsel = lane & 15;
    const int kof = (lane >> 4) * 8;
    bf16x8 af[4], bfr[4];
#pragma unroll
    for (int m = 0; m < 4; ++m)
        af[m] = *(const bf16x8*)(As + (size_t)(m * 16 + rsel) * 32 + kof);
#pragma unroll
    for (int n = 0; n < 4; ++n)
        bfr[n] = *(const bf16x8*)(Bs + (size_t)(wc * 64 + n * 16 + rsel) * 32 + kof);
#pragma unroll
    for (int m = 0; m < 4; ++m)
#pragma unroll
        for (int n = 0; n < 4; ++n)
            acc[m][n] = __builtin_amdgcn_mfma_f32_16x16x32_bf16(af[m], bfr[n], acc[m][n], 0, 0, 0);
}

// kernel A: conv1 + bias + relu + LN -> plain padded bf16 h
__global__ __launch_bounds__(256) void k_conv_ln1(
        const unsigned short* __restrict__ xplain, const unsigned short* __restrict__ xpplain,
        const unsigned short* __restrict__ bt,
        const float* __restrict__ b1, const float* __restrict__ g1, const float* __restrict__ be1,
        unsigned short* __restrict__ h0, unsigned short* __restrict__ h1, unsigned short* __restrict__ h2) {
    __shared__ unsigned short As[2][64 * 32];
    __shared__ unsigned short Bs[2][256 * 32];
    __shared__ float2 red[4][64];

    const int pred = blockIdx.y;
    const unsigned short* A  = (pred < 2) ? xplain : xpplain;
    const unsigned short* Bm = bt + (size_t)pred * 256 * KH;
    unsigned short* hout = (pred == 0) ? h0 : (pred == 1) ? h1 : h2;

    const int rowBase = blockIdx.x * 64;
    const int bb = rowBase >> 8;
    const int l0 = rowBase & 255;
    const int browPad = bb * PADL + l0;
    const int tid = threadIdx.x;
    const int lane = tid & 63;
    const int wc = tid >> 6;
    const int rsel = lane & 15;
    const int lhi = lane >> 4;

    f32x4 acc[4][4];
#pragma unroll
    for (int m = 0; m < 4; ++m)
#pragma unroll
        for (int n = 0; n < 4; ++n) acc[m][n] = (f32x4){0.f, 0.f, 0.f, 0.f};

    stage_tile(A, Bm, browPad, 0, As[0], Bs[0], tid);
    __syncthreads();
    int cur = 0;
    for (int kt = 32; kt < KH; kt += 32) {
        stage_tile(A, Bm, browPad, kt, As[cur ^ 1], Bs[cur ^ 1], tid);
        compute_tile(As[cur], Bs[cur], lane, wc, acc);
        __syncthreads();
        cur ^= 1;
    }
    compute_tile(As[cur], Bs[cur], lane, wc, acc);

    float bcol[4], gcol[4], becol[4];
#pragma unroll
    for (int n = 0; n < 4; ++n) {
        int c = wc * 64 + n * 16 + rsel;
        bcol[n] = b1[pred * 256 + c];
        gcol[n] = g1[pred * 256 + c];
        becol[n] = be1[pred * 256 + c];
    }

#pragma unroll
    for (int m = 0; m < 4; ++m)
#pragma unroll
        for (int r = 0; r < 4; ++r) {
            float s = 0.f, s2 = 0.f;
#pragma unroll
            for (int n = 0; n < 4; ++n) {
                float v = fmaxf(acc[m][n][r] + bcol[n], 0.f);
                s += v; s2 += v * v;
            }
#pragma unroll
            for (int o = 1; o < 16; o <<= 1) { s += __shfl_xor(s, o); s2 += __shfl_xor(s2, o); }
            if (rsel == 0) red[wc][m * 16 + lhi * 4 + r] = make_float2(s, s2);
        }
    __syncthreads();
    if (tid < 64) {
        float2 a0 = red[0][tid], a1 = red[1][tid], a2 = red[2][tid], a3 = red[3][tid];
        red[0][tid] = make_float2(a0.x + a1.x + a2.x + a3.x, a0.y + a1.y + a2.y + a3.y);
    }
    __syncthreads();

#pragma unroll
    for (int m = 0; m < 4; ++m)
#pragma unroll
        for (int r = 0; r < 4; ++r) {
            int rl = m * 16 + lhi * 4 + r;
            float2 t = red[0][rl];
            float mean = t.x * (1.f / 256.f);
            float var = t.y * (1.f / 256.f) - mean * mean;
            float inv = rsqrtf(var + EPS_);
            int l = l0 + rl;
            size_t row = (size_t)bb * PADL + 1 + l;
#pragma unroll
            for (int n = 0; n < 4; ++n) {
                float v = fmaxf(acc[m][n][r] + bcol[n], 0.f);
                float h = (v - mean) * inv * gcol[n] + becol[n];
                int c = wc * 64 + n * 16 + rsel;
                hout[row * 256 + c] = f2bf(h);
                if (l == 0)   hout[((size_t)bb * PADL) * 256 + c] = 0;
                if (l == 255) hout[((size_t)bb * PADL + 257) * 256 + c] = 0;
            }
        }
}

// kernel B: conv2 + bias + relu + LN + dot(wl) + mask -> predictions
__global__ __launch_bounds__(256) void k_conv_ln2(
        const unsigned short* __restrict__ h0, const unsigned short* __restrict__ h1,
        const unsigned short* __restrict__ h2, const unsigned short* __restrict__ bt,
        const float* __restrict__ b2, const float* __restrict__ g2, const float* __restrict__ be2,
        const float* __restrict__ wl, const float* __restrict__ bl,
        const char* __restrict__ mask, float* __restrict__ outp) {
    __shared__ unsigned short As[2][64 * 32];
    __shared__ unsigned short Bs[2][256 * 32];
    __shared__ float2 red[4][64];
    __shared__ float red2[4][64];

    const int pred = blockIdx.y;
    const unsigned short* A  = (pred == 0) ? h0 : (pred == 1) ? h1 : h2;
    const unsigned short* Bm = bt + (size_t)(768 + pred * 256) * KH;

    const int rowBase = blockIdx.x * 64;
    const int bb = rowBase >> 8;
    const int l0 = rowBase & 255;
    const int browPad = bb * PADL + l0;
    const int tid = threadIdx.x;
    const int lane = tid & 63;
    const int wc = tid >> 6;
    const int rsel = lane & 15;
    const int lhi = lane >> 4;

    f32x4 acc[4][4];
#pragma unroll
    for (int m = 0; m < 4; ++m)
#pragma unroll
        for (int n = 0; n < 4; ++n) acc[m][n] = (f32x4){0.f, 0.f, 0.f, 0.f};

    stage_tile(A, Bm, browPad, 0, As[0], Bs[0], tid);
    __syncthreads();
    int cur = 0;
    for (int kt = 32; kt < KH; kt += 32) {
        stage_tile(A, Bm, browPad, kt, As[cur ^ 1], Bs[cur ^ 1], tid);
        compute_tile(As[cur], Bs[cur], lane, wc, acc);
        __syncthreads();
        cur ^= 1;
    }
    compute_tile(As[cur], Bs[cur], lane, wc, acc);

    float bcol[4], gcol[4], becol[4], wcol[4];
#pragma unroll
    for (int n = 0; n < 4; ++n) {
        int c = wc * 64 + n * 16 + rsel;
        bcol[n] = b2[pred * 256 + c];
        gcol[n] = g2[pred * 256 + c];
        becol[n] = be2[pred * 256 + c];
        wcol[n] = wl[pred * 256 + c];
    }

#pragma unroll
    for (int m = 0; m < 4; ++m)
#pragma unroll
        for (int r = 0; r < 4; ++r) {
            float s = 0.f, s2 = 0.f;
#pragma unroll
            for (int n = 0; n < 4; ++n) {
                float v = fmaxf(acc[m][n][r] + bcol[n], 0.f);
                s += v; s2 += v * v;
            }
#pragma unroll
            for (int o = 1; o < 16; o <<= 1) { s += __shfl_xor(s, o); s2 += __shfl_xor(s2, o); }
            if (rsel == 0) red[wc][m * 16 + lhi * 4 + r] = make_float2(s, s2);
        }
    __syncthreads();
    if (tid < 64) {
        float2 a0 = red[0][tid], a1 = red[1][tid], a2 = red[2][tid], a3 = red[3][tid];
        red[0][tid] = make_float2(a0.x + a1.x + a2.x + a3.x, a0.y + a1.y + a2.y + a3.y);
    }
    __syncthreads();

#pragma unroll
    for (int m = 0; m < 4; ++m)
#pragma unroll
        for (int r = 0; r < 4; ++r) {
            int rl = m * 16 + lhi * 4 + r;
            float2 t = red[0][rl];
            float mean = t.x * (1.f / 256.f);
            float var = t.y * (1.f / 256.f) - mean * mean;
            float inv = rsqrtf(var + EPS_);
            float d = 0.f;
#pragma unroll
            for (int n = 0; n < 4; ++n) {
                float v = fmaxf(acc[m][n][r] + bcol[n], 0.f);
                float h = (v - mean) * inv * gcol[n] + becol[n];
                d += h * wcol[n];
            }
#pragma unroll
            for (int o = 1; o < 16; o <<= 1) d += __shfl_xor(d, o);
            if (rsel == 0) red2[wc][rl] = d;
        }
    __syncthreads();
    if (tid < 64) {
        int p = rowBase + tid;
        float o = red2[0][tid] + red2[1][tid] + red2[2][tid] + red2[3][tid] + bl[pred];
        if (mask[p]) o = 0.f;
        outp[(size_t)pred * P_TOT + p] = o;
    }
}

// ---------------- length regulate gather + mel mask (LDS cumsum + float4 rows)
__global__ __launch_bounds__(256) void k_gather(const float* __restrict__ xpe,
                                                const int* __restrict__ cum,
                                                float* __restrict__ out,
                                                float* __restrict__ maskout) {
    int b = blockIdx.y;
    int t0 = blockIdx.x * 16;
    __shared__ int sc[256];
    int tid = threadIdx.x;
    sc[tid] = cum[b * 256 + tid];
    __syncthreads();
    int mel = sc[255];
    int wv = tid >> 6, lane = tid & 63;
#pragma unroll
    for (int it = 0; it < 4; ++it) {
        int t = t0 + it * 4 + wv;
        int lo = 0, hi = 256;
        while (lo < hi) { int mid = (lo + hi) >> 1; if (sc[mid] <= t) lo = mid + 1; else hi = mid; }
        bool valid = t < mel;
        int idx = lo > 255 ? 255 : lo;
        f32x4 v = (f32x4){0.f, 0.f, 0.f, 0.f};
        if (valid) v = *(const f32x4*)(xpe + ((size_t)(b * 256 + idx)) * 256 + lane * 4);
        *(f32x4*)(out + ((size_t)(b * 2048 + t)) * 256 + lane * 4) = v;
        if (lane == 0) maskout[b * 2048 + t] = valid ? 0.f : 1.f;
    }
}

extern "C" void kernel_launch(void* const* d_in, const int* in_sizes, int n_in,
                              void* d_out, int out_size, void* d_ws, size_t ws_size,
                              hipStream_t stream) {
    const float* x     = (const float*)d_in[0];
    const float* pt    = (const float*)d_in[1];
    const float* et    = (const float*)d_in[2];
    const float* w1    = (const float*)d_in[3];
    const float* b1    = (const float*)d_in[4];
    const float* g1    = (const float*)d_in[5];
    const float* be1   = (const float*)d_in[6];
    const float* w2    = (const float*)d_in[7];
    const float* b2    = (const float*)d_in[8];
    const float* g2    = (const float*)d_in[9];
    const float* be2   = (const float*)d_in[10];
    const float* wl    = (const float*)d_in[11];
    const float* bl    = (const float*)d_in[12];
    const float* pbins = (const float*)d_in[13];
    const float* ebins = (const float*)d_in[14];
    const float* pemb  = (const float*)d_in[15];
    const float* eemb  = (const float*)d_in[16];
    const char*  mask  = (const char*)d_in[17];
    const int*   dur   = (const int*)d_in[18];

    char* ws = (char*)d_ws;
    // padded plain buffers: 32*258*256*2B = 4,227,072 B each
    unsigned short* xplain  = (unsigned short*)(ws + 0);
    unsigned short* xpplain = (unsigned short*)(ws + 8388608);
    unsigned short* h0      = (unsigned short*)(ws + 16777216);
    unsigned short* h1      = (unsigned short*)(ws + 25165824);
    unsigned short* h2      = (unsigned short*)(ws + 33554432);
    float*          xpe     = (float*)(ws + 41943040);
    unsigned short* btall   = (unsigned short*)(ws + 52428800);
    int*            cum     = (int*)(ws + 56623104);

    float* out        = (float*)d_out;
    float* out_pred   = out + 16777216;           // log_dur | pitch | energy (8192 each)
    float* out_mellen = out + 16801792;
    float* out_mask   = out + 16801824;

    hipLaunchKernelGGL(k_wtrans, dim3(288), dim3(256), 0, stream, w1, w2, btall);
    hipLaunchKernelGGL(k_cumsum, dim3(32), dim3(256), 0, stream, dur, cum, out_mellen);
    hipLaunchKernelGGL(k_embed, dim3(8192), dim3(256), 0, stream,
                       x, pt, et, pbins, ebins, pemb, eemb, xplain, xpplain, xpe);

    hipLaunchKernelGGL(k_conv_ln1, dim3(128, 3), dim3(256), 0, stream,
                       xplain, xpplain, btall, b1, g1, be1, h0, h1, h2);
    hipLaunchKernelGGL(k_conv_ln2, dim3(128, 3), dim3(256), 0, stream,
                       h0, h1, h2, btall, b2, g2, be2, wl, bl, mask, out_pred);

    hipLaunchKernelGGL(k_gather, dim3(128, 32), dim3(256), 0, stream, xpe, cum, out, out_mask);
}